// Round 17
// baseline (76.207 us; speedup 1.0000x reference)
//
#include <hip/hip_runtime.h>
#include <math.h>

#define PP 4096
#define CDIM 256
#define NHEADS 4
#define HD 64
#define PW 104
#define PH 98
#define PLANE (PW * PH)
#define PAD 17

typedef unsigned int u32t;
typedef unsigned short u16t;
typedef _Float16 f16;
typedef __attribute__((ext_vector_type(2))) _Float16 f16x2;
typedef __attribute__((ext_vector_type(8))) _Float16 f16x8;
typedef __attribute__((ext_vector_type(4))) float f32x4;

#if defined(__has_builtin)
#if __has_builtin(__builtin_amdgcn_fdot2)
#define HAS_FDOT2 1
#endif
#endif

__device__ __forceinline__ float wave_sum(float v) {
#pragma unroll
  for (int off = 32; off > 0; off >>= 1) v += __shfl_down(v, off);
  return v;
}

__device__ __forceinline__ u32t pkh(float lo, float hi) {
  return __builtin_bit_cast(u32t, __builtin_amdgcn_cvt_pkrtz(lo, hi));
}
__device__ __forceinline__ f16x2 pk2h(float lo, float hi) {
  return __builtin_bit_cast(f16x2, __builtin_amdgcn_cvt_pkrtz(lo, hi));
}
__device__ __forceinline__ f16x2 h2(u32t w) {
  return __builtin_bit_cast(f16x2, w);
}

// ---- prep: pack x f32 [b][c][p] -> f16 chunked [b][c32][p][8] + avg partials
__global__ __launch_bounds__(256) void k_prep(const float* __restrict__ x,
                                              u16t* __restrict__ xb,
                                              float* __restrict__ pavg) {
  const int p = blockIdx.x * 256 + threadIdx.x;
  const int c32 = blockIdx.y;  // 0..31
  const int b = blockIdx.z;
  const float* s = x + ((size_t)b * CDIM + c32 * 8) * PP + p;
  float f[8];
#pragma unroll
  for (int j = 0; j < 8; ++j) f[j] = s[(size_t)j * PP];
  u32t u[4];
#pragma unroll
  for (int jw = 0; jw < 4; ++jw) u[jw] = pkh(f[2 * jw], f[2 * jw + 1]);
  *(uint4*)&xb[(((size_t)b * 32 + c32) * PP + p) * 8] = *(const uint4*)u;
  __shared__ float red[4][8];
  const int lane = threadIdx.x & 63, wid = threadIdx.x >> 6;
#pragma unroll
  for (int j = 0; j < 8; ++j) {
    const float sj = wave_sum(f[j]);
    if (lane == 0) red[wid][j] = sj;
  }
  __syncthreads();
  if (threadIdx.x < 8) {
    const int j = threadIdx.x;
    pavg[(((size_t)b * 32 + c32) * 16 + blockIdx.x) * 8 + j] =
        red[0][j] + red[1][j] + red[2][j] + red[3][j];
  }
}

// ---- wpack: blocks 0..95 pack Wq/Wk/Wv; 96..351 Wog/Rg/Cg; 352 dirs+tabs --
__global__ __launch_bounds__(256) void k_wpack(
    const float* __restrict__ Wq, const float* __restrict__ Wk,
    const float* __restrict__ Wv, const float* __restrict__ Wo,
    const float* __restrict__ bo, const float* __restrict__ gnw,
    const float* __restrict__ gnb, const float* __restrict__ pavg,
    const float* __restrict__ dirW, const float* __restrict__ dirb,
    u16t* __restrict__ Wa, u16t* __restrict__ Wog, float* __restrict__ Rg,
    float* __restrict__ Cg, float* __restrict__ wtab, int* __restrict__ otab) {
  if (blockIdx.x < 96) {
    const int c32 = blockIdx.x & 31;
    const int m = blockIdx.x >> 5;  // 0..2
    const int o = threadIdx.x;
    const float* W = (m == 0 ? Wq : (m == 1 ? Wk : Wv));
    const float4 a = *(const float4*)&W[o * CDIM + c32 * 8];
    const float4 bq = *(const float4*)&W[o * CDIM + c32 * 8 + 4];
    u32t u[4];
    u[0] = pkh(a.x, a.y);
    u[1] = pkh(a.z, a.w);
    u[2] = pkh(bq.x, bq.y);
    u[3] = pkh(bq.z, bq.w);
    *(uint4*)&Wa[(((size_t)m * 32 + c32) * CDIM + o) * 8] = *(const uint4*)u;
  } else if (blockIdx.x < 352) {
    const int o = blockIdx.x - 96;  // 0..255
    const int c = threadIdx.x;      // 0..255 ; wave = GN group
    const float wv = Wo[o * CDIM + c];
    const float wg = wv * gnw[c];
    Wog[(((size_t)(c >> 3)) * CDIM + o) * 8 + (c & 7)] =
        __builtin_bit_cast(u16t, (f16)wg);
    const float rsum = wave_sum(wg);
    const float csum = wave_sum(wv * gnb[c]);
    __shared__ float redc[4];
    const int lane = c & 63, g = c >> 6;
    if (lane == 0) {
      Rg[o * 4 + g] = rsum;
      redc[g] = csum;
    }
    __syncthreads();
    if (threadIdx.x == 0)
      Cg[o] = bo[o] + redc[0] + redc[1] + redc[2] + redc[3];
  } else {
    __shared__ float avg_l[2][256];
    __shared__ float dv[2][32];
    const int c = threadIdx.x;
#pragma unroll
    for (int b = 0; b < 2; ++b) {
      float s = 0.f;
      for (int pb = 0; pb < 16; ++pb)
        s += pavg[(((size_t)b * 32 + (c >> 3)) * 16 + pb) * 8 + (c & 7)];
      avg_l[b][c] = s * (1.0f / PP);
    }
    __syncthreads();
    if (threadIdx.x < 64) {
      const int b = threadIdx.x >> 5, row = threadIdx.x & 31;
      const float* w = dirW + row * CDIM;
      float s = dirb[row];
      for (int cc = 0; cc < CDIM; ++cc) s = fmaf(avg_l[b][cc], w[cc], s);
      dv[b][row] = s;
    }
    __syncthreads();
    if (threadIdx.x < 32) {
      const int b = threadIdx.x >> 4, hs = threadIdx.x & 15;
      float vx = dv[b][hs * 2], vy = dv[b][hs * 2 + 1];
      const float n = fmaxf(sqrtf(vx * vx + vy * vy), 1e-6f);
      vx /= n;
      vy /= n;
      const int bh = b * 4 + (hs >> 2);
      const int s = hs & 3;
#pragma unroll
      for (int mm = 0; mm < 8; ++mm) {
        const float t = -0.5f + mm * (1.0f / 7.0f);
        const float dxp = vx * t * 31.5f;
        const float dyp = vy * t * 31.5f;
        const float fxf = floorf(dxp), fyf = floorf(dyp);
        const float fx = dxp - fxf, fy = dyp - fyf;
        const int kidx = bh * 32 + s * 8 + mm;
        wtab[kidx * 4 + 0] = (1.0f - fx) * (1.0f - fy);
        wtab[kidx * 4 + 1] = fx * (1.0f - fy);
        wtab[kidx * 4 + 2] = (1.0f - fx) * fy;
        wtab[kidx * 4 + 3] = fx * fy;
        otab[kidx] = (int)fyf * PW + (int)fxf;
      }
    }
  }
}

// ---- fused QKV MFMA GEMM (f16); Q flat, K/V into PADDED planes ----
__global__ __launch_bounds__(256) void k_mfma_qkv(const u16t* __restrict__ Wa,
                                                  const u16t* __restrict__ xb,
                                                  u16t* __restrict__ Qc,
                                                  u16t* __restrict__ Kp,
                                                  u16t* __restrict__ Vp) {
  const int p0 = blockIdx.x * 64;
  const int ot = blockIdx.y;     // 0..11
  const int m = ot >> 2;         // 0=Q,1=K,2=V
  const int ob = (ot & 3) * 64;  // o base within matrix
  const int b = blockIdx.z;
  const int l = threadIdx.x & 63, w = threadIdx.x >> 6;
  const int lm = l & 15, lk = l >> 4;
  f32x4 acc[4] = {};
  const u16t* Ab = Wa + ((size_t)m * 32) * CDIM * 8 + (ob + w * 16 + lm) * 8;
  const u16t* Bb = xb + ((size_t)b * 32) * PP * 8 + ((size_t)p0 + lm) * 8;
  for (int c0 = 0; c0 < CDIM; c0 += 32) {
    const int ch = (c0 >> 3) + lk;
    const f16x8 af = *(const f16x8*)(Ab + (size_t)ch * CDIM * 8);
#pragma unroll
    for (int j = 0; j < 4; ++j) {
      const f16x8 bf = *(const f16x8*)(Bb + ((size_t)ch * PP + j * 16) * 8);
      acc[j] = __builtin_amdgcn_mfma_f32_16x16x32_f16(af, bf, acc[j], 0, 0, 0);
    }
  }
  const int c32i = (ob >> 3) + w * 2 + (lk >> 1);
#pragma unroll
  for (int j = 0; j < 4; ++j) {
    const u32t lo = pkh(acc[j][0], acc[j][1]);
    const u32t hi = pkh(acc[j][2], acc[j][3]);
    const u32t plo = __shfl_xor(lo, 16);
    const u32t phi = __shfl_xor(hi, 16);
    if ((l & 16) == 0) {
      uint4 v;
      v.x = lo;
      v.y = hi;
      v.z = plo;
      v.w = phi;
      const int pp = p0 + j * 16 + lm;
      if (m == 0) {
        *(uint4*)&Qc[(((size_t)b * 32 + c32i) * PP + pp) * 8] = v;
      } else {
        const int y = pp >> 6, xx = pp & 63;
        const size_t ei = ((size_t)b * 32 + c32i) * PLANE +
                          (size_t)(y + PAD) * PW + (xx + PAD);
        u16t* d = (m == 1 ? Kp : Vp);
        *(uint4*)&d[ei * 8] = v;
      }
    }
  }
}

// ---- pad: fill replicated borders of all 128 padded planes ----
__global__ __launch_bounds__(128) void k_pad(u16t* __restrict__ Kp,
                                             u16t* __restrict__ Vp) {
  const int py = blockIdx.x;   // 0..97
  const int pi2 = blockIdx.y;  // 0..127
  const int px = threadIdx.x;
  if (px >= PW) return;
  if (py >= PAD && py < PAD + 64 && px >= PAD && px < PAD + 64) return;
  const int sy = min(max(py - PAD, 0), 63);
  const int sx = min(max(px - PAD, 0), 63);
  u16t* T = (pi2 < 64) ? Kp : Vp;
  const size_t base = (size_t)(pi2 & 63) * PLANE;
  const uint4 v =
      *(const uint4*)&T[(base + (size_t)(sy + PAD) * PW + (sx + PAD)) * 8];
  *(uint4*)&T[(base + (size_t)py * PW + px) * 8] = v;
}

__device__ __forceinline__ float dot8h(const f16x2* q, uint4 v) {
#ifdef HAS_FDOT2
  float a = __builtin_amdgcn_fdot2(q[0], h2(v.x), 0.f, false);
  a = __builtin_amdgcn_fdot2(q[1], h2(v.y), a, false);
  a = __builtin_amdgcn_fdot2(q[2], h2(v.z), a, false);
  a = __builtin_amdgcn_fdot2(q[3], h2(v.w), a, false);
  return a;
#else
  float a = 0.f;
  const u32t wv[4] = {v.x, v.y, v.z, v.w};
#pragma unroll
  for (int j = 0; j < 4; ++j) {
    const f16x2 hh = h2(wv[j]);
    a = fmaf((float)q[j].x, (float)hh.x, a);
    a = fmaf((float)q[j].y, (float)hh.y, a);
  }
  return a;
#endif
}

// ---- fused attention, online-softmax, UNIFORM taps on padded planes:
// wave = 16 pixels x 4 quarters (16 d each); block 256 = 64 pixels.
// FLAT grid 512, XCD swizzle bh = id&7. Per k: uniform weights + uniform
// offset from tables -> branchless, 8 loads with shared vaddr + imm offsets.
__global__ __launch_bounds__(256) void k_attn(
    const uint4* __restrict__ Qc, const uint4* __restrict__ Kp4,
    const uint4* __restrict__ Vp4, const float* __restrict__ wtab,
    const int* __restrict__ otab, u16t* __restrict__ Obc,
    float* __restrict__ part) {
  __shared__ float wl[32][4];
  __shared__ int ol[32];
  __shared__ float r1[4], r2[4];
  const int tid = threadIdx.x;
  const int lane = tid & 63, wv = tid >> 6;
  const int p4 = lane & 15;       // pixel within wave
  const int qt = lane >> 4;       // d-quarter 0..3
  const int pl = wv * 16 + p4;    // p-local 0..63
  const int bh = blockIdx.x & 7;  // XCD swizzle
  const int pb = blockIdx.x >> 3;
  const int p = pb * 64 + pl;
  const int b = bh >> 2, h = bh & 3;
  if (tid < 32) {
    const int kidx = bh * 32 + tid;
    const float4 w4 = *(const float4*)&wtab[kidx * 4];
    wl[tid][0] = w4.x;
    wl[tid][1] = w4.y;
    wl[tid][2] = w4.z;
    wl[tid][3] = w4.w;
    ol[tid] = otab[kidx];
  }
  __syncthreads();
  // Q: my 2 chunks (16 d) as 8 f16x2
  f16x2 qh[8];
  {
    const uint4* Qp = Qc + ((size_t)b * 32 + h * 8 + qt * 2) * PP + p;
#pragma unroll
    for (int cc = 0; cc < 2; ++cc) {
      const uint4 qv = Qp[(size_t)cc * PP];
      qh[cc * 4 + 0] = h2(qv.x);
      qh[cc * 4 + 1] = h2(qv.y);
      qh[cc * 4 + 2] = h2(qv.z);
      qh[cc * 4 + 3] = h2(qv.w);
    }
  }
  const int ibase = ((p >> 6) + PAD) * PW + ((p & 63) + PAD);
  const uint4* Kb0 = Kp4 + (size_t)(b * 32 + h * 8 + qt * 2) * PLANE;
  const uint4* Kb1 = Kb0 + PLANE;
  const uint4* Vb0 = Vp4 + (size_t)(b * 32 + h * 8 + qt * 2) * PLANE;
  const uint4* Vb1 = Vb0 + PLANE;

  float m = -1e30f, sum = 0.f;
  float acc[16] = {};
#pragma unroll 2
  for (int k = 0; k < 32; ++k) {
    const float w00 = wl[k][0], w01 = wl[k][1];
    const float w10 = wl[k][2], w11 = wl[k][3];
    const int idx = ibase + ol[k];
    // --- K gather (4 taps x 2 chunks, shared vaddr + imm offsets) + dots ---
    const uint4* ka = Kb0 + idx;
    const uint4* kb = Kb1 + idx;
    const uint4 ta0 = ka[0], ta1 = ka[1], ta2 = ka[PW], ta3 = ka[PW + 1];
    const uint4 tb0 = kb[0], tb1 = kb[1], tb2 = kb[PW], tb3 = kb[PW + 1];
    float a00 = dot8h(qh, ta0) + dot8h(qh + 4, tb0);
    float a01 = dot8h(qh, ta1) + dot8h(qh + 4, tb1);
    float a10 = dot8h(qh, ta2) + dot8h(qh + 4, tb2);
    float a11 = dot8h(qh, ta3) + dot8h(qh + 4, tb3);
    float lgv = w00 * a00 + w01 * a01 + w10 * a10 + w11 * a11;
    lgv += __shfl_xor(lgv, 16);
    lgv += __shfl_xor(lgv, 32);
    lgv *= 0.125f;  // SCALE
    // --- online softmax update with deferred rescale (THR = 8) ---
    if (__any(lgv - m > 8.0f)) {
      const float mnew = fmaxf(m, lgv);
      const float sc = __expf(m - mnew);
      sum *= sc;
#pragma unroll
      for (int d = 0; d < 16; ++d) acc[d] *= sc;
      m = mnew;
    }
    const float w = __expf(lgv - m);
    sum += w;
    // --- V gather + weighted accumulate ---
    const uint4* va = Vb0 + idx;
    const uint4* vb = Vb1 + idx;
    const uint4 v00a = va[0], v01a = va[1], v10a = va[PW], v11a = va[PW + 1];
    const uint4 v00b = vb[0], v01b = vb[1], v10b = vb[PW], v11b = vb[PW + 1];
#ifdef HAS_FDOT2
    const f16x2 wt01 = pk2h(w * w00, w * w01);
    const f16x2 wt23 = pk2h(w * w10, w * w11);
#pragma unroll
    for (int cc = 0; cc < 2; ++cc) {
      const uint4 t0 = cc ? v00b : v00a;
      const uint4 t1 = cc ? v01b : v01a;
      const uint4 t2 = cc ? v10b : v10a;
      const uint4 t3 = cc ? v11b : v11a;
      const u32t a0[4] = {t0.x, t0.y, t0.z, t0.w};
      const u32t a1[4] = {t1.x, t1.y, t1.z, t1.w};
      const u32t a2[4] = {t2.x, t2.y, t2.z, t2.w};
      const u32t a3[4] = {t3.x, t3.y, t3.z, t3.w};
      float* a = acc + cc * 8;
#pragma unroll
      for (int j = 0; j < 4; ++j) {
        const f16x2 p01l = h2(__builtin_amdgcn_perm(a1[j], a0[j], 0x05040100u));
        const f16x2 p23l = h2(__builtin_amdgcn_perm(a3[j], a2[j], 0x05040100u));
        const f16x2 p01h = h2(__builtin_amdgcn_perm(a1[j], a0[j], 0x07060302u));
        const f16x2 p23h = h2(__builtin_amdgcn_perm(a3[j], a2[j], 0x07060302u));
        a[2 * j] = __builtin_amdgcn_fdot2(
            wt01, p01l, __builtin_amdgcn_fdot2(wt23, p23l, a[2 * j], false),
            false);
        a[2 * j + 1] = __builtin_amdgcn_fdot2(
            wt01, p01h,
            __builtin_amdgcn_fdot2(wt23, p23h, a[2 * j + 1], false), false);
      }
    }
#else
    const float u00 = w * w00, u01 = w * w01, u10 = w * w10, u11 = w * w11;
#pragma unroll
    for (int cc = 0; cc < 2; ++cc) {
      const uint4 t0 = cc ? v00b : v00a;
      const uint4 t1 = cc ? v01b : v01a;
      const uint4 t2 = cc ? v10b : v10a;
      const uint4 t3 = cc ? v11b : v11a;
      float* a = acc + cc * 8;
#pragma unroll
      for (int j = 0; j < 4; ++j) {
        const f16x2 h0 = h2((&t0.x)[j]), h1 = h2((&t1.x)[j]);
        const f16x2 hh2 = h2((&t2.x)[j]), h3 = h2((&t3.x)[j]);
        a[2 * j] = fmaf(
            u00, (float)h0.x,
            fmaf(u01, (float)h1.x,
                 fmaf(u10, (float)hh2.x, fmaf(u11, (float)h3.x, a[2 * j]))));
        a[2 * j + 1] =
            fmaf(u00, (float)h0.y,
                 fmaf(u01, (float)h1.y,
                      fmaf(u10, (float)hh2.y,
                           fmaf(u11, (float)h3.y, a[2 * j + 1]))));
      }
    }
#endif
  }
  // normalize
  const float inv = 1.0f / sum;
#pragma unroll
  for (int d = 0; d < 16; ++d) acc[d] *= inv;
  // store Obc (f16 chunked): 2 uint4 per lane
#pragma unroll
  for (int cc = 0; cc < 2; ++cc) {
    const int c32 = h * 8 + qt * 2 + cc;
    u32t u[4];
#pragma unroll
    for (int jw = 0; jw < 4; ++jw)
      u[jw] = pkh(acc[cc * 8 + 2 * jw], acc[cc * 8 + 2 * jw + 1]);
    *(uint4*)&Obc[(((size_t)b * 32 + c32) * PP + p) * 8] = *(const uint4*)u;
  }
  // GN partials: block covers 64 p x 64 d
  float s1 = 0.f, s2 = 0.f;
#pragma unroll
  for (int d = 0; d < 16; ++d) {
    s1 += acc[d];
    s2 += acc[d] * acc[d];
  }
  s1 = wave_sum(s1);
  s2 = wave_sum(s2);
  if (lane == 0) {
    r1[wv] = s1;
    r2[wv] = s2;
  }
  __syncthreads();
  if (tid == 0) {
    const size_t slot = (size_t)bh * 64 + pb;
    part[slot * 2] = r1[0] + r1[1] + r1[2] + r1[3];
    part[slot * 2 + 1] = r2[0] + r2[1] + r2[2] + r2[3];
  }
}

// ---- final MFMA GEMM (f16) with GN-stats prologue ----
__global__ __launch_bounds__(256) void k_mfma_out(
    const u16t* __restrict__ Wog, const u16t* __restrict__ Obc,
    const float* __restrict__ part, const float* __restrict__ Rg,
    const float* __restrict__ Cg, const float* __restrict__ x,
    float* __restrict__ outp) {
  __shared__ float mul[8], rsl[8], sraw[16];
  {
    const int t = threadIdx.x;
    const int bhx = t >> 5, idx = t & 31;
    float s1 = part[((size_t)(bhx * 64 + idx)) * 2] +
               part[((size_t)(bhx * 64 + 32 + idx)) * 2];
    float s2 = part[((size_t)(bhx * 64 + idx)) * 2 + 1] +
               part[((size_t)(bhx * 64 + 32 + idx)) * 2 + 1];
#pragma unroll
    for (int off = 16; off > 0; off >>= 1) {
      s1 += __shfl_down(s1, off, 32);
      s2 += __shfl_down(s2, off, 32);
    }
    if (idx == 0) {
      sraw[bhx * 2] = s1;
      sraw[bhx * 2 + 1] = s2;
    }
  }
  __syncthreads();
  if (threadIdx.x < 8) {
    const int t = threadIdx.x;
    const float inv = 1.0f / (HD * PP);
    const float mu = sraw[t * 2] * inv;
    const float var = sraw[t * 2 + 1] * inv - mu * mu;
    mul[t] = mu;
    rsl[t] = rsqrtf(var + 1e-5f);
  }
  __syncthreads();
  const int p0 = blockIdx.x * 64;
  const int ob = blockIdx.y * 64;
  const int b = blockIdx.z;
  const int l = threadIdx.x & 63, w = threadIdx.x >> 6;
  const int lm = l & 15, lk = l >> 4;
  f32x4 acc[4][4] = {};  // [g][j]
  const u16t* Ab = Wog + (ob + w * 16 + lm) * 8;
  const u16t* Bb = Obc + ((size_t)b * 32) * PP * 8 + ((size_t)p0 + lm) * 8;
#pragma unroll
  for (int c0 = 0; c0 < CDIM; c0 += 32) {
    const int g = c0 >> 6;
    const int ch = (c0 >> 3) + lk;
    const f16x8 af = *(const f16x8*)(Ab + (size_t)ch * CDIM * 8);
#pragma unroll
    for (int j = 0; j < 4; ++j) {
      const f16x8 bf = *(const f16x8*)(Bb + ((size_t)ch * PP + j * 16) * 8);
      acc[g][j] =
          __builtin_amdgcn_mfma_f32_16x16x32_f16(af, bf, acc[g][j], 0, 0, 0);
    }
  }
  const float mu0 = mul[b * 4 + 0], rs0 = rsl[b * 4 + 0];
  const float mu1 = mul[b * 4 + 1], rs1 = rsl[b * 4 + 1];
  const float mu2 = mul[b * 4 + 2], rs2 = rsl[b * 4 + 2];
  const float mu3 = mul[b * 4 + 3], rs3 = rsl[b * 4 + 3];
  float obias[4];
#pragma unroll
  for (int r = 0; r < 4; ++r) {
    const int o = ob + w * 16 + lk * 4 + r;
    const float4 rg = *(const float4*)&Rg[o * 4];
    obias[r] = Cg[o] - (rs0 * mu0 * rg.x + rs1 * mu1 * rg.y +
                        rs2 * mu2 * rg.z + rs3 * mu3 * rg.w);
  }
#pragma unroll
  for (int j = 0; j < 4; ++j) {
    const int p = p0 + j * 16 + lm;
#pragma unroll
    for (int r = 0; r < 4; ++r) {
      const int o = ob + w * 16 + lk * 4 + r;
      const float v = rs0 * acc[0][j][r] + rs1 * acc[1][j][r] +
                      rs2 * acc[2][j][r] + rs3 * acc[3][j][r];
      const size_t idx = ((size_t)b * CDIM + o) * PP + p;
      outp[idx] = v + obias[r] + x[idx];
    }
  }
}

extern "C" void kernel_launch(void* const* d_in, const int* in_sizes, int n_in,
                              void* d_out, int out_size, void* d_ws,
                              size_t ws_size, hipStream_t stream) {
  const float* x = (const float*)d_in[0];
  const float* Wq = (const float*)d_in[1];
  const float* Wk = (const float*)d_in[2];
  const float* Wv = (const float*)d_in[3];
  const float* Wo = (const float*)d_in[4];
  const float* bo = (const float*)d_in[5];
  const float* dirW = (const float*)d_in[6];
  const float* dirb = (const float*)d_in[7];
  const float* gnw = (const float*)d_in[8];
  const float* gnb = (const float*)d_in[9];
  float* outp = (float*)d_out;

  float* ws = (float*)d_ws;
  float* wtab = ws + 512;         // 1024 floats
  int* otab = (int*)(ws + 1536);  // 256 ints
  float* pavg = ws + 2048;        // 8192
  float* part = ws + 10240;       // 1024 (512 slots x 2)
  float* Rg = ws + 12288;         // 1024
  float* Cg = ws + 13312;         // 256
  u16t* xb = (u16t*)(ws + 16384);     // 2,097,152 u16
  u16t* Wa = (u16t*)(ws + 1064960);   // 196,608 u16
  u16t* Wog = (u16t*)(ws + 1163264);  // 65,536 u16
  u16t* Qc = (u16t*)(ws + 1228800);   // 2,097,152 u16 -> ends 2,277,376
  u16t* Kp = (u16t*)(ws + 2277376);   // 64*PLANE*8 u16 -> ends 4,886,528
  u16t* Vp = (u16t*)(ws + 4886528);   // -> ends 7,495,680
  u16t* Obc = (u16t*)(ws + 7495680);  // 2,097,152 u16 -> ends 8,544,256

  k_prep<<<dim3(16, 32, 2), dim3(256), 0, stream>>>(x, xb, pavg);
  k_wpack<<<dim3(353), dim3(256), 0, stream>>>(Wq, Wk, Wv, Wo, bo, gnw, gnb,
                                               pavg, dirW, dirb, Wa, Wog, Rg,
                                               Cg, wtab, otab);
  k_mfma_qkv<<<dim3(64, 12, 2), dim3(256), 0, stream>>>(Wa, xb, Qc, Kp, Vp);
  k_pad<<<dim3(PH, 128), dim3(128), 0, stream>>>(Kp, Vp);
  k_attn<<<dim3(512), dim3(256), 0, stream>>>(
      (const uint4*)Qc, (const uint4*)Kp, (const uint4*)Vp, wtab, otab, Obc,
      part);
  k_mfma_out<<<dim3(64, 4, 2), dim3(256), 0, stream>>>(Wog, Obc, part, Rg, Cg,
                                                       x, outp);
}

// Round 18
// 65.587 us; speedup vs baseline: 1.1619x; 1.1619x over previous
//
#include <hip/hip_runtime.h>
#include <math.h>

#define PP 4096
#define CDIM 256
#define NHEADS 4
#define HD 64

typedef unsigned int u32t;
typedef unsigned short u16t;
typedef _Float16 f16;
typedef __attribute__((ext_vector_type(2))) _Float16 f16x2;
typedef __attribute__((ext_vector_type(8))) _Float16 f16x8;
typedef __attribute__((ext_vector_type(4))) float f32x4;

#if defined(__has_builtin)
#if __has_builtin(__builtin_amdgcn_fdot2)
#define HAS_FDOT2 1
#endif
#endif

__device__ __forceinline__ float wave_sum(float v) {
#pragma unroll
  for (int off = 32; off > 0; off >>= 1) v += __shfl_down(v, off);
  return v;
}

__device__ __forceinline__ u32t pkh(float lo, float hi) {
  return __builtin_bit_cast(u32t, __builtin_amdgcn_cvt_pkrtz(lo, hi));
}
__device__ __forceinline__ f16x2 pk2h(float lo, float hi) {
  return __builtin_bit_cast(f16x2, __builtin_amdgcn_cvt_pkrtz(lo, hi));
}
__device__ __forceinline__ f16x2 h2(u32t w) {
  return __builtin_bit_cast(f16x2, w);
}

// ---- fused prep + wpack (independent halves):
// blocks 0..1023: pack x -> f16 chunked [b][c32][p][8] + avg partials
// blocks 1024..1119: pack Wq/Wk/Wv -> Wa(f16)
// blocks 1120..1375: Wog/Rg/Cg
__global__ __launch_bounds__(256) void k_prepw(
    const float* __restrict__ x, const float* __restrict__ Wq,
    const float* __restrict__ Wk, const float* __restrict__ Wv,
    const float* __restrict__ Wo, const float* __restrict__ bo,
    const float* __restrict__ gnw, const float* __restrict__ gnb,
    u16t* __restrict__ xb, float* __restrict__ pavg, u16t* __restrict__ Wa,
    u16t* __restrict__ Wog, float* __restrict__ Rg, float* __restrict__ Cg) {
  const int id = blockIdx.x;
  if (id < 1024) {
    const int pblk = id & 15;
    const int c32 = (id >> 4) & 31;
    const int b = id >> 9;
    const int p = pblk * 256 + threadIdx.x;
    const float* s = x + ((size_t)b * CDIM + c32 * 8) * PP + p;
    float f[8];
#pragma unroll
    for (int j = 0; j < 8; ++j) f[j] = s[(size_t)j * PP];
    u32t u[4];
#pragma unroll
    for (int jw = 0; jw < 4; ++jw) u[jw] = pkh(f[2 * jw], f[2 * jw + 1]);
    *(uint4*)&xb[(((size_t)b * 32 + c32) * PP + p) * 8] = *(const uint4*)u;
    __shared__ float red[4][8];
    const int lane = threadIdx.x & 63, wid = threadIdx.x >> 6;
#pragma unroll
    for (int j = 0; j < 8; ++j) {
      const float sj = wave_sum(f[j]);
      if (lane == 0) red[wid][j] = sj;
    }
    __syncthreads();
    if (threadIdx.x < 8) {
      const int j = threadIdx.x;
      pavg[(((size_t)b * 32 + c32) * 16 + pblk) * 8 + j] =
          red[0][j] + red[1][j] + red[2][j] + red[3][j];
    }
  } else if (id < 1120) {
    const int wid = id - 1024;  // 0..95
    const int c32 = wid & 31;
    const int m = wid >> 5;  // 0..2
    const int o = threadIdx.x;
    const float* W = (m == 0 ? Wq : (m == 1 ? Wk : Wv));
    const float4 a = *(const float4*)&W[o * CDIM + c32 * 8];
    const float4 bq = *(const float4*)&W[o * CDIM + c32 * 8 + 4];
    u32t u[4];
    u[0] = pkh(a.x, a.y);
    u[1] = pkh(a.z, a.w);
    u[2] = pkh(bq.x, bq.y);
    u[3] = pkh(bq.z, bq.w);
    *(uint4*)&Wa[(((size_t)m * 32 + c32) * CDIM + o) * 8] = *(const uint4*)u;
  } else {
    const int o = id - 1120;    // 0..255
    const int c = threadIdx.x;  // 0..255 ; wave = GN group
    const float wv = Wo[o * CDIM + c];
    const float wg = wv * gnw[c];
    Wog[(((size_t)(c >> 3)) * CDIM + o) * 8 + (c & 7)] =
        __builtin_bit_cast(u16t, (f16)wg);
    const float rsum = wave_sum(wg);
    const float csum = wave_sum(wv * gnb[c]);
    __shared__ float redc[4];
    const int lane = c & 63, g = c >> 6;
    if (lane == 0) {
      Rg[o * 4 + g] = rsum;
      redc[g] = csum;
    }
    __syncthreads();
    if (threadIdx.x == 0)
      Cg[o] = bo[o] + redc[0] + redc[1] + redc[2] + redc[3];
  }
}

// ---- fused QKV MFMA GEMM (f16) + dirs (grid y==12) ----
__global__ __launch_bounds__(256) void k_mfma_qkv(
    const u16t* __restrict__ Wa, const u16t* __restrict__ xb,
    const float* __restrict__ pavg, const float* __restrict__ dirW,
    const float* __restrict__ dirb, u16t* __restrict__ Qc,
    u16t* __restrict__ Kc, u16t* __restrict__ Vc, float* __restrict__ offs) {
  if (blockIdx.y == 12) {
    if (blockIdx.x != 0 || blockIdx.z != 0) return;
    // dirs: reduce avg partials -> linear -> normalize -> pixel offsets
    __shared__ float avg_l[2][256];
    __shared__ float dv[2][32];
    const int c = threadIdx.x;
#pragma unroll
    for (int b = 0; b < 2; ++b) {
      float s = 0.f;
      for (int pb = 0; pb < 16; ++pb)
        s += pavg[(((size_t)b * 32 + (c >> 3)) * 16 + pb) * 8 + (c & 7)];
      avg_l[b][c] = s * (1.0f / PP);
    }
    __syncthreads();
    if (threadIdx.x < 64) {
      const int b = threadIdx.x >> 5, row = threadIdx.x & 31;
      const float* w = dirW + row * CDIM;
      float s = dirb[row];
      for (int cc = 0; cc < CDIM; ++cc) s = fmaf(avg_l[b][cc], w[cc], s);
      dv[b][row] = s;
    }
    __syncthreads();
    if (threadIdx.x < 32) {
      const int b = threadIdx.x >> 4, hs = threadIdx.x & 15;
      float vx = dv[b][hs * 2], vy = dv[b][hs * 2 + 1];
      const float n = fmaxf(sqrtf(vx * vx + vy * vy), 1e-6f);
      vx /= n;
      vy /= n;
#pragma unroll
      for (int mm = 0; mm < 8; ++mm) {
        const float t = -0.5f + mm * (1.0f / 7.0f);
        const int o = ((b * 16 + hs) * 8 + mm) * 2;
        offs[o] = vx * t * 31.5f;  // pixel units
        offs[o + 1] = vy * t * 31.5f;
      }
    }
    return;
  }
  const int p0 = blockIdx.x * 64;
  const int ot = blockIdx.y;     // 0..11
  const int m = ot >> 2;         // 0=Q,1=K,2=V
  const int ob = (ot & 3) * 64;  // o base within matrix
  const int b = blockIdx.z;
  const int l = threadIdx.x & 63, w = threadIdx.x >> 6;
  const int lm = l & 15, lk = l >> 4;
  f32x4 acc[4] = {};
  const u16t* Ab = Wa + ((size_t)m * 32) * CDIM * 8 + (ob + w * 16 + lm) * 8;
  const u16t* Bb = xb + ((size_t)b * 32) * PP * 8 + ((size_t)p0 + lm) * 8;
  for (int c0 = 0; c0 < CDIM; c0 += 32) {
    const int ch = (c0 >> 3) + lk;
    const f16x8 af = *(const f16x8*)(Ab + (size_t)ch * CDIM * 8);
#pragma unroll
    for (int j = 0; j < 4; ++j) {
      const f16x8 bf = *(const f16x8*)(Bb + ((size_t)ch * PP + j * 16) * 8);
      acc[j] = __builtin_amdgcn_mfma_f32_16x16x32_f16(af, bf, acc[j], 0, 0, 0);
    }
  }
  u16t* dst = (m == 0 ? Qc : (m == 1 ? Kc : Vc));
  const int c32i = (ob >> 3) + w * 2 + (lk >> 1);
#pragma unroll
  for (int j = 0; j < 4; ++j) {
    const u32t lo = pkh(acc[j][0], acc[j][1]);
    const u32t hi = pkh(acc[j][2], acc[j][3]);
    const u32t plo = __shfl_xor(lo, 16);
    const u32t phi = __shfl_xor(hi, 16);
    if ((l & 16) == 0) {
      uint4 v;
      v.x = lo;
      v.y = hi;
      v.z = plo;
      v.w = phi;
      *(uint4*)&dst[(((size_t)b * 32 + c32i) * PP + p0 + j * 16 + lm) * 8] = v;
    }
  }
}

// ---------------- cheap pixel-space bilinear setup ----------------
struct Samp {
  int i00, i01, i10, i11;
  float w00, w01, w10, w11;
};
__device__ __forceinline__ Samp samp_px(float xif, float yif, float dxp,
                                        float dyp) {
  const float px = fminf(fmaxf(xif + dxp, 0.f), 63.f);
  const float py = fminf(fmaxf(yif + dyp, 0.f), 63.f);
  const float x0f = floorf(px), y0f = floorf(py);
  const float fx = px - x0f, fy = py - y0f;
  const int x0 = (int)x0f, y0 = (int)y0f;
  const int dx1 = (x0 < 63) ? 1 : 0;
  const int dy1 = (y0 < 63) ? 64 : 0;
  Samp sp;
  sp.i00 = y0 * 64 + x0;
  sp.i01 = sp.i00 + dx1;
  sp.i10 = sp.i00 + dy1;
  sp.i11 = sp.i10 + dx1;
  const float ifx = 1.0f - fx, ify = 1.0f - fy;
  sp.w00 = ifx * ify;
  sp.w01 = fx * ify;
  sp.w10 = ifx * fy;
  sp.w11 = fx * fy;
  return sp;
}

__device__ __forceinline__ float dot8h(const f16x2* q, uint4 v) {
#ifdef HAS_FDOT2
  float a = __builtin_amdgcn_fdot2(q[0], h2(v.x), 0.f, false);
  a = __builtin_amdgcn_fdot2(q[1], h2(v.y), a, false);
  a = __builtin_amdgcn_fdot2(q[2], h2(v.z), a, false);
  a = __builtin_amdgcn_fdot2(q[3], h2(v.w), a, false);
  return a;
#else
  float a = 0.f;
  const u32t wv[4] = {v.x, v.y, v.z, v.w};
#pragma unroll
  for (int j = 0; j < 4; ++j) {
    const f16x2 hh = h2(wv[j]);
    a = fmaf((float)q[j].x, (float)hh.x, a);
    a = fmaf((float)q[j].y, (float)hh.y, a);
  }
  return a;
#endif
}

// ---- fused attention, ONLINE-SOFTMAX single pass (f16 data):
// wave = 16 pixels x 4 quarters (16 d each); block 256 = 64 pixels.
// FLAT grid 512 with XCD swizzle: bh = id&7 so all 64 blocks of one bh
// land on one XCD (round-robin dispatch) -> K+V+Q (1.5 MB) stays in its L2.
__global__ __launch_bounds__(256) void k_attn(const uint4* __restrict__ Qc,
                                              const uint4* __restrict__ Kc,
                                              const uint4* __restrict__ Vc,
                                              const float* __restrict__ offs,
                                              u16t* __restrict__ Obc,
                                              float* __restrict__ part) {
  __shared__ float offl[64];
  __shared__ float r1[4], r2[4];
  const int tid = threadIdx.x;
  const int lane = tid & 63, wv = tid >> 6;
  const int p4 = lane & 15;       // pixel within wave
  const int qt = lane >> 4;       // d-quarter 0..3
  const int pl = wv * 16 + p4;    // p-local 0..63
  const int bh = blockIdx.x & 7;  // XCD swizzle: same bh -> same XCD
  const int pb = blockIdx.x >> 3;
  const int p = pb * 64 + pl;
  const int b = bh >> 2, h = bh & 3;
  if (tid < 64) offl[tid] = offs[(b * 16 + h * 4) * 16 + tid];
  __syncthreads();
  // Q: my 2 chunks (16 d) as 8 f16x2
  f16x2 qh[8];
  {
    const uint4* Qp = Qc + ((size_t)b * 32 + h * 8 + qt * 2) * PP + p;
#pragma unroll
    for (int cc = 0; cc < 2; ++cc) {
      const uint4 qv = Qp[(size_t)cc * PP];
      qh[cc * 4 + 0] = h2(qv.x);
      qh[cc * 4 + 1] = h2(qv.y);
      qh[cc * 4 + 2] = h2(qv.z);
      qh[cc * 4 + 3] = h2(qv.w);
    }
  }
  const float xif = (float)(p & 63), yif = (float)(p >> 6);
  const uint4* Kb = Kc + ((size_t)b * 32 + h * 8 + qt * 2) * PP;
  const uint4* Vb = Vc + ((size_t)b * 32 + h * 8 + qt * 2) * PP;

  float m = -1e30f, sum = 0.f;
  float acc[16] = {};
#pragma unroll 4
  for (int k = 0; k < 32; ++k) {
    const Samp sp = samp_px(xif, yif, offl[k * 2], offl[k * 2 + 1]);
    // --- K gather + dot (16 d of this quarter) ---
    float a00 = 0.f, a01 = 0.f, a10 = 0.f, a11 = 0.f;
#pragma unroll
    for (int cc = 0; cc < 2; ++cc) {
      const uint4* base = Kb + (size_t)cc * PP;
      const uint4 t00 = base[sp.i00];
      const uint4 t01 = base[sp.i01];
      const uint4 t10 = base[sp.i10];
      const uint4 t11 = base[sp.i11];
      a00 += dot8h(qh + cc * 4, t00);
      a01 += dot8h(qh + cc * 4, t01);
      a10 += dot8h(qh + cc * 4, t10);
      a11 += dot8h(qh + cc * 4, t11);
    }
    float lgv = sp.w00 * a00 + sp.w01 * a01 + sp.w10 * a10 + sp.w11 * a11;
    lgv += __shfl_xor(lgv, 16);
    lgv += __shfl_xor(lgv, 32);
    lgv *= 0.125f;  // SCALE; all 64 lanes hold their pixel's logit
    // --- online softmax update with deferred rescale (THR = 8) ---
    if (__any(lgv - m > 8.0f)) {
      const float mnew = fmaxf(m, lgv);
      const float sc = __expf(m - mnew);
      sum *= sc;
#pragma unroll
      for (int d = 0; d < 16; ++d) acc[d] *= sc;
      m = mnew;
    }
    const float w = __expf(lgv - m);
    sum += w;
    // --- V gather + weighted accumulate ---
#ifdef HAS_FDOT2
    const f16x2 wt01 = pk2h(w * sp.w00, w * sp.w01);
    const f16x2 wt23 = pk2h(w * sp.w10, w * sp.w11);
#pragma unroll
    for (int cc = 0; cc < 2; ++cc) {
      const uint4* base = Vb + (size_t)cc * PP;
      const uint4 t00 = base[sp.i00];
      const uint4 t01 = base[sp.i01];
      const uint4 t10 = base[sp.i10];
      const uint4 t11 = base[sp.i11];
      const u32t a0[4] = {t00.x, t00.y, t00.z, t00.w};
      const u32t a1[4] = {t01.x, t01.y, t01.z, t01.w};
      const u32t a2[4] = {t10.x, t10.y, t10.z, t10.w};
      const u32t a3[4] = {t11.x, t11.y, t11.z, t11.w};
      float* a = acc + cc * 8;
#pragma unroll
      for (int j = 0; j < 4; ++j) {
        const f16x2 p01l = h2(__builtin_amdgcn_perm(a1[j], a0[j], 0x05040100u));
        const f16x2 p23l = h2(__builtin_amdgcn_perm(a3[j], a2[j], 0x05040100u));
        const f16x2 p01h = h2(__builtin_amdgcn_perm(a1[j], a0[j], 0x07060302u));
        const f16x2 p23h = h2(__builtin_amdgcn_perm(a3[j], a2[j], 0x07060302u));
        a[2 * j] = __builtin_amdgcn_fdot2(
            wt01, p01l, __builtin_amdgcn_fdot2(wt23, p23l, a[2 * j], false),
            false);
        a[2 * j + 1] = __builtin_amdgcn_fdot2(
            wt01, p01h,
            __builtin_amdgcn_fdot2(wt23, p23h, a[2 * j + 1], false), false);
      }
    }
#else
    const float w00 = w * sp.w00, w01 = w * sp.w01;
    const float w10 = w * sp.w10, w11 = w * sp.w11;
#pragma unroll
    for (int cc = 0; cc < 2; ++cc) {
      const uint4* base = Vb + (size_t)cc * PP;
      const uint4 t00 = base[sp.i00];
      const uint4 t01 = base[sp.i01];
      const uint4 t10 = base[sp.i10];
      const uint4 t11 = base[sp.i11];
      const u32t a0[4] = {t00.x, t00.y, t00.z, t00.w};
      const u32t a1[4] = {t01.x, t01.y, t01.z, t01.w};
      const u32t a2[4] = {t10.x, t10.y, t10.z, t10.w};
      const u32t a3[4] = {t11.x, t11.y, t11.z, t11.w};
      float* a = acc + cc * 8;
#pragma unroll
      for (int j = 0; j < 4; ++j) {
        const f16x2 h0 = h2(a0[j]), h1 = h2(a1[j]), hh2 = h2(a2[j]),
                    h3 = h2(a3[j]);
        a[2 * j] = fmaf(
            w00, (float)h0.x,
            fmaf(w01, (float)h1.x,
                 fmaf(w10, (float)hh2.x, fmaf(w11, (float)h3.x, a[2 * j]))));
        a[2 * j + 1] =
            fmaf(w00, (float)h0.y,
                 fmaf(w01, (float)h1.y,
                      fmaf(w10, (float)hh2.y,
                           fmaf(w11, (float)h3.y, a[2 * j + 1]))));
      }
    }
#endif
  }
  // normalize
  const float inv = 1.0f / sum;
#pragma unroll
  for (int d = 0; d < 16; ++d) acc[d] *= inv;
  // store Obc (f16 chunked): 2 uint4 per lane
#pragma unroll
  for (int cc = 0; cc < 2; ++cc) {
    const int c32 = h * 8 + qt * 2 + cc;
    u32t u[4];
#pragma unroll
    for (int jw = 0; jw < 4; ++jw)
      u[jw] = pkh(acc[cc * 8 + 2 * jw], acc[cc * 8 + 2 * jw + 1]);
    *(uint4*)&Obc[(((size_t)b * 32 + c32) * PP + p) * 8] = *(const uint4*)u;
  }
  // GN partials: block covers 64 p x 64 d
  float s1 = 0.f, s2 = 0.f;
#pragma unroll
  for (int d = 0; d < 16; ++d) {
    s1 += acc[d];
    s2 += acc[d] * acc[d];
  }
  s1 = wave_sum(s1);
  s2 = wave_sum(s2);
  if (lane == 0) {
    r1[wv] = s1;
    r2[wv] = s2;
  }
  __syncthreads();
  if (tid == 0) {
    const size_t slot = (size_t)bh * 64 + pb;
    part[slot * 2] = r1[0] + r1[1] + r1[2] + r1[3];
    part[slot * 2 + 1] = r2[0] + r2[1] + r2[2] + r2[3];
  }
}

// ---- final MFMA GEMM (f16) with GN-stats prologue ----
__global__ __launch_bounds__(256) void k_mfma_out(
    const u16t* __restrict__ Wog, const u16t* __restrict__ Obc,
    const float* __restrict__ part, const float* __restrict__ Rg,
    const float* __restrict__ Cg, const float* __restrict__ x,
    float* __restrict__ outp) {
  __shared__ float mul[8], rsl[8], sraw[16];
  {
    const int t = threadIdx.x;
    const int bhx = t >> 5, idx = t & 31;
    float s1 = part[((size_t)(bhx * 64 + idx)) * 2] +
               part[((size_t)(bhx * 64 + 32 + idx)) * 2];
    float s2 = part[((size_t)(bhx * 64 + idx)) * 2 + 1] +
               part[((size_t)(bhx * 64 + 32 + idx)) * 2 + 1];
#pragma unroll
    for (int off = 16; off > 0; off >>= 1) {
      s1 += __shfl_down(s1, off, 32);
      s2 += __shfl_down(s2, off, 32);
    }
    if (idx == 0) {
      sraw[bhx * 2] = s1;
      sraw[bhx * 2 + 1] = s2;
    }
  }
  __syncthreads();
  if (threadIdx.x < 8) {
    const int t = threadIdx.x;
    const float inv = 1.0f / (HD * PP);
    const float mu = sraw[t * 2] * inv;
    const float var = sraw[t * 2 + 1] * inv - mu * mu;
    mul[t] = mu;
    rsl[t] = rsqrtf(var + 1e-5f);
  }
  __syncthreads();
  const int p0 = blockIdx.x * 64;
  const int ob = blockIdx.y * 64;
  const int b = blockIdx.z;
  const int l = threadIdx.x & 63, w = threadIdx.x >> 6;
  const int lm = l & 15, lk = l >> 4;
  f32x4 acc[4][4] = {};  // [g][j]
  const u16t* Ab = Wog + (ob + w * 16 + lm) * 8;
  const u16t* Bb = Obc + ((size_t)b * 32) * PP * 8 + ((size_t)p0 + lm) * 8;
#pragma unroll
  for (int c0 = 0; c0 < CDIM; c0 += 32) {
    const int g = c0 >> 6;
    const int ch = (c0 >> 3) + lk;
    const f16x8 af = *(const f16x8*)(Ab + (size_t)ch * CDIM * 8);
#pragma unroll
    for (int j = 0; j < 4; ++j) {
      const f16x8 bf = *(const f16x8*)(Bb + ((size_t)ch * PP + j * 16) * 8);
      acc[g][j] =
          __builtin_amdgcn_mfma_f32_16x16x32_f16(af, bf, acc[g][j], 0, 0, 0);
    }
  }
  const float mu0 = mul[b * 4 + 0], rs0 = rsl[b * 4 + 0];
  const float mu1 = mul[b * 4 + 1], rs1 = rsl[b * 4 + 1];
  const float mu2 = mul[b * 4 + 2], rs2 = rsl[b * 4 + 2];
  const float mu3 = mul[b * 4 + 3], rs3 = rsl[b * 4 + 3];
  float obias[4];
#pragma unroll
  for (int r = 0; r < 4; ++r) {
    const int o = ob + w * 16 + lk * 4 + r;
    const float4 rg = *(const float4*)&Rg[o * 4];
    obias[r] = Cg[o] - (rs0 * mu0 * rg.x + rs1 * mu1 * rg.y +
                        rs2 * mu2 * rg.z + rs3 * mu3 * rg.w);
  }
#pragma unroll
  for (int j = 0; j < 4; ++j) {
    const int p = p0 + j * 16 + lm;
#pragma unroll
    for (int r = 0; r < 4; ++r) {
      const int o = ob + w * 16 + lk * 4 + r;
      const float v = rs0 * acc[0][j][r] + rs1 * acc[1][j][r] +
                      rs2 * acc[2][j][r] + rs3 * acc[3][j][r];
      const size_t idx = ((size_t)b * CDIM + o) * PP + p;
      outp[idx] = v + obias[r] + x[idx];
    }
  }
}

extern "C" void kernel_launch(void* const* d_in, const int* in_sizes, int n_in,
                              void* d_out, int out_size, void* d_ws,
                              size_t ws_size, hipStream_t stream) {
  const float* x = (const float*)d_in[0];
  const float* Wq = (const float*)d_in[1];
  const float* Wk = (const float*)d_in[2];
  const float* Wv = (const float*)d_in[3];
  const float* Wo = (const float*)d_in[4];
  const float* bo = (const float*)d_in[5];
  const float* dirW = (const float*)d_in[6];
  const float* dirb = (const float*)d_in[7];
  const float* gnw = (const float*)d_in[8];
  const float* gnb = (const float*)d_in[9];
  float* outp = (float*)d_out;

  float* ws = (float*)d_ws;
  float* offs = ws + 512;    // 1024 floats
  float* pavg = ws + 2048;   // 8192
  float* part = ws + 10240;  // 1024 (512 slots x 2)
  float* Rg = ws + 12288;    // 1024
  float* Cg = ws + 13312;    // 256
  u16t* xb = (u16t*)(ws + 16384);     // 2,097,152 u16
  u16t* Wa = (u16t*)(ws + 1064960);   // 196,608 u16
  u16t* Wog = (u16t*)(ws + 1163264);  // 65,536 u16
  u16t* Qc = (u16t*)(ws + 1228800);   // 2,097,152 u16
  u16t* Kc = (u16t*)(ws + 2277376);
  u16t* Vc = (u16t*)(ws + 3325952);
  u16t* Obc = (u16t*)(ws + 4374528);  // 2,097,152 u16

  k_prepw<<<dim3(1376), dim3(256), 0, stream>>>(x, Wq, Wk, Wv, Wo, bo, gnw,
                                                gnb, xb, pavg, Wa, Wog, Rg, Cg);
  k_mfma_qkv<<<dim3(64, 13, 2), dim3(256), 0, stream>>>(
      Wa, xb, pavg, dirW, dirb, Qc, Kc, Vc, offs);
  k_attn<<<dim3(512), dim3(256), 0, stream>>>(
      (const uint4*)Qc, (const uint4*)Kc, (const uint4*)Vc, offs, Obc, part);
  k_mfma_out<<<dim3(64, 4, 2), dim3(256), 0, stream>>>(Wog, Obc, part, Rg, Cg,
                                                       x, outp);
}